// Round 11
// baseline (224.073 us; speedup 1.0000x reference)
//
#include <hip/hip_runtime.h>
#include <math.h>

typedef _Float16 f16;
typedef __attribute__((ext_vector_type(8))) _Float16 f16x8;
typedef __attribute__((ext_vector_type(4))) _Float16 f16x4;
typedef __attribute__((ext_vector_type(4))) float f32x4;

#define NSEQ 4096
#define DIN 1024
#define DOUT 1024

// async global->LDS, 16B per lane; LDS dest must be wave-uniform base + lane*16
__device__ __forceinline__ void load16(const void* g, void* l) {
    __builtin_amdgcn_global_load_lds(
        (const __attribute__((address_space(1))) unsigned int*)g,
        (__attribute__((address_space(3))) unsigned int*)l, 16, 0, 0);
}

// C[M,N] = scale * (A[M,K] @ B[N,K]^T).  A,B f16.  128x128 tile, BK=64,
// single-buffered (R5-measured best: ~784 TF plateau at this structure).
// z: A += z*aStrideZ, B += z*bStrideZ; C = cz.
// EPI 1 (QKV): normal store, except z==tz writes f16 C^T to TC (ld=ldt).
// EPI 2 (S):   C = exp(acc*scale) f16 + per-(row, wave-col-half) partial sums
//              to Sums[row*64 + bx*2 + wn/64] (written once, no atomics).
// EPI 3 (PV fused split-K=2): sibling blocks z=0/1 share tile (bx,by).
//   First finisher publishes its fp32 partial via agent-scope atomic stores,
//   release-stores a flag; the winner computes row-sum inverses while
//   waiting, acquire-spins, reads the partial with agent-scope atomic loads,
//   and writes (acc+partial)*inv to c0. Deterministic (a+b commutative).
//   R9/R10 FAILURE ROOT CAUSE (fixed in launch): flags overlaid Wt, which
//   prep wrote AFTER the memset -> garbage protocol state. flags now live
//   in a dedicated, never-aliased region.
template <typename OutT, int EPI>
__global__ __launch_bounds__(256, 2)
void gemm_bt(const f16* __restrict__ A, const f16* __restrict__ B,
             OutT* __restrict__ c0, OutT* __restrict__ c1,
             OutT* __restrict__ c2, OutT* __restrict__ c3,
             int M, int N, int K, int lda, int ldb, int ldc, float scale,
             long aStrideZ, long bStrideZ,
             f16* __restrict__ TC, int tz, int ldt,
             float* __restrict__ Sums, float* __restrict__ scratch,
             int* __restrict__ flags)
{
    const int z = blockIdx.z;
    A += (long)z * aStrideZ;
    B += (long)z * bStrideZ;
    OutT* C = z == 0 ? c0 : (z == 1 ? c1 : (z == 2 ? c2 : c3));
    __shared__ f16 As[2 * 128 * 32];
    __shared__ f16 Bs[2 * 128 * 32];

    // ---- XCD patch swizzle (bijective remap of (bx,by)) ----
    int gx = gridDim.x;
    int bid = blockIdx.y * gx + blockIdx.x;
    int xcd = bid & 7, s = bid >> 3;
    int px = s & 7, rest = s >> 3;
    int py = rest & 3, chunk = rest >> 2;
    int pg = xcd + (chunk << 3);          // global patch id
    int pcols = gx >> 3;                  // patches per row (power of 2)
    int lp = 31 - __clz(pcols);
    int bx = ((pg & (pcols - 1)) << 3) + px;
    int by = ((pg >> lp) << 2) + py;

    const int t    = threadIdx.x;
    const int lane = t & 63;
    const int wave = t >> 6;
    const int wm   = (wave >> 1) * 64;
    const int wn   = (wave & 1) * 64;
    const int tile_m = by * 128;
    const int tile_n = bx * 128;
    const int quad = lane >> 4;
    const int l16  = lane & 15;
    // staging: thread t -> LDS chunk t (row t/4); global col chunk XOR-swizzled
    const int srow = t >> 2;
    const int scol = ((t & 3) ^ (srow & 3)) * 8;
    const int qx8 = (quad ^ (l16 & 3)) * 8;

    f32x4 acc[4][4];
#pragma unroll
    for (int i = 0; i < 4; i++)
#pragma unroll
        for (int j = 0; j < 4; j++)
            acc[i][j] = (f32x4){0.f, 0.f, 0.f, 0.f};

    const f16* Ab = A + (long)(tile_m + srow) * lda + scol;
    const f16* Bb = B + (long)(tile_n + srow) * ldb + scol;
    f16* Asd = As + t * 8;
    f16* Bsd = Bs + t * 8;

    for (int k0 = 0; k0 < K; k0 += 64) {
        load16(Ab + k0, Asd);
        load16(Ab + (long)64 * lda + k0, Asd + 2048);
        load16(Ab + k0 + 32, Asd + 4096);
        load16(Ab + (long)64 * lda + k0 + 32, Asd + 4096 + 2048);
        load16(Bb + k0, Bsd);
        load16(Bb + (long)64 * ldb + k0, Bsd + 2048);
        load16(Bb + k0 + 32, Bsd + 4096);
        load16(Bb + (long)64 * ldb + k0 + 32, Bsd + 4096 + 2048);
        __syncthreads();  // drains vmcnt(0); 32 MFMA/wave per drain
#pragma unroll
        for (int p = 0; p < 2; p++) {
            f16x8 a[4], b[4];
#pragma unroll
            for (int i = 0; i < 4; i++)
                a[i] = *(const f16x8*)(As + p * 4096 + (wm + i * 16 + l16) * 32 + qx8);
#pragma unroll
            for (int j = 0; j < 4; j++)
                b[j] = *(const f16x8*)(Bs + p * 4096 + (wn + j * 16 + l16) * 32 + qx8);
#pragma unroll
            for (int i = 0; i < 4; i++)
#pragma unroll
                for (int j = 0; j < 4; j++)
                    acc[i][j] = __builtin_amdgcn_mfma_f32_16x16x32_f16(
                        a[i], b[j], acc[i][j], 0, 0, 0);
        }
        __syncthreads();
    }
    // epilogue: D row = quad*4 + reg, col = lane&15  (verified m89/m91 layout)
    if (EPI == 1) {
        if (z == tz) {
            // transposed f16 write: TC[col*ldt + row], 8B per store (4 rows)
#pragma unroll
            for (int i = 0; i < 4; i++)
#pragma unroll
                for (int j = 0; j < 4; j++) {
                    f16x4 o;
#pragma unroll
                    for (int r = 0; r < 4; r++) o[r] = (f16)(acc[i][j][r] * scale);
                    int row0 = tile_m + wm + i * 16 + quad * 4;
                    int col  = tile_n + wn + j * 16 + l16;
                    *(f16x4*)(TC + (long)col * ldt + row0) = o;
                }
        } else {
#pragma unroll
            for (int i = 0; i < 4; i++)
#pragma unroll
                for (int j = 0; j < 4; j++)
#pragma unroll
                    for (int r = 0; r < 4; r++) {
                        int row = tile_m + wm + i * 16 + quad * 4 + r;
                        int col = tile_n + wn + j * 16 + l16;
                        C[(long)row * ldc + col] = (OutT)(acc[i][j][r] * scale);
                    }
        }
    } else if (EPI == 2) {
        // P' = exp(s*scale), plus per-row partial sums over this wave's 64 cols
        const int bxs = bx * 2 + (wn >> 6);
#pragma unroll
        for (int i = 0; i < 4; i++) {
            float rs[4] = {0.f, 0.f, 0.f, 0.f};
#pragma unroll
            for (int j = 0; j < 4; j++)
#pragma unroll
                for (int r = 0; r < 4; r++) {
                    float e = __expf(acc[i][j][r] * scale);
                    int row = tile_m + wm + i * 16 + quad * 4 + r;
                    int col = tile_n + wn + j * 16 + l16;
                    C[(long)row * ldc + col] = (OutT)e;
                    rs[r] += e;
                }
#pragma unroll
            for (int msk = 1; msk < 16; msk <<= 1)
#pragma unroll
                for (int r = 0; r < 4; r++)
                    rs[r] += __shfl_xor(rs[r], msk, 64);
            if (l16 == 0)
#pragma unroll
                for (int r = 0; r < 4; r++) {
                    int row = tile_m + wm + i * 16 + quad * 4 + r;
                    Sums[(long)row * 64 + bxs] = rs[r];
                }
        }
    } else if (EPI == 3) {
        const int tile = by * 8 + bx;       // gx==8 -> 256 tiles
        __shared__ int role_s;
        if (t == 0) role_s = atomicAdd(&flags[2 * tile], 1);
        __syncthreads();
        float* scr = scratch + (long)tile * (128 * 128);
        if (role_s == 0) {
            // first finisher: publish partial with agent-scope (coherent) stores
#pragma unroll
            for (int i = 0; i < 4; i++)
#pragma unroll
                for (int j = 0; j < 4; j++)
#pragma unroll
                    for (int r = 0; r < 4; r++) {
                        int ri = wm + i * 16 + quad * 4 + r;
                        int ci = wn + j * 16 + l16;
                        __hip_atomic_store(&scr[ri * 128 + ci], acc[i][j][r],
                                           __ATOMIC_RELAXED,
                                           __HIP_MEMORY_SCOPE_AGENT);
                    }
            __syncthreads();   // all threads' stores issued & drained
            __threadfence();
            if (t == 0)
                __hip_atomic_store(&flags[2 * tile + 1], 1, __ATOMIC_RELEASE,
                                   __HIP_MEMORY_SCOPE_AGENT);
        } else {
            // winner: compute row-sum inverses while the sibling finishes
            float* invl = (float*)As;       // 512 B over dead LDS
            {
                float sv[32];
                const int rbase = wave * 32;
#pragma unroll
                for (int r = 0; r < 32; r++)
                    sv[r] = Sums[(long)(tile_m + rbase + r) * 64 + lane];
#pragma unroll
                for (int r = 0; r < 32; r++) {
                    float sm = sv[r];
#pragma unroll
                    for (int msk = 1; msk < 64; msk <<= 1)
                        sm += __shfl_xor(sm, msk, 64);
                    if (lane == 0) invl[rbase + r] = 1.f / sm;
                }
            }
            if (t == 0)
                while (__hip_atomic_load(&flags[2 * tile + 1], __ATOMIC_ACQUIRE,
                                         __HIP_MEMORY_SCOPE_AGENT) == 0)
                    __builtin_amdgcn_s_sleep(2);
            __syncthreads();
            float* Co = (float*)c0;
#pragma unroll
            for (int i = 0; i < 4; i++)
#pragma unroll
                for (int j = 0; j < 4; j++)
#pragma unroll
                    for (int r = 0; r < 4; r++) {
                        int ri = wm + i * 16 + quad * 4 + r;
                        int ci = wn + j * 16 + l16;
                        // agent-scope load: bypass this XCD's (stale) L1/L2
                        float p = __hip_atomic_load(&scr[ri * 128 + ci],
                                                    __ATOMIC_RELAXED,
                                                    __HIP_MEMORY_SCOPE_AGENT);
                        Co[(long)(tile_m + ri) * ldc + tile_n + ci] =
                            (acc[i][j][r] + p) * invl[ri];
                    }
        }
    }
}

// z<3: transpose+cast W_z fp32[in][out] -> Wt_z f16[out][in]; z==3: cast x->f16
__global__ void prep(const float* __restrict__ x,
                     const float* __restrict__ W0, const float* __restrict__ W1,
                     const float* __restrict__ W2,
                     f16* __restrict__ xb, f16* __restrict__ Wt) {
    if (blockIdx.z == 3) {
        long base = ((long)(blockIdx.y * 16 + blockIdx.x) * 256 + threadIdx.x) * 4;
#pragma unroll
        for (int it = 0; it < 16; it++) {
            long i = base + (long)it * (256 * 256 * 4);
            f32x4 v = *(const f32x4*)(x + i);
            f16x4 o;
            o.x = (f16)v.x; o.y = (f16)v.y; o.z = (f16)v.z; o.w = (f16)v.w;
            *(f16x4*)(xb + i) = o;
        }
        return;
    }
    __shared__ f16 tile[64][65];
    const float* W = blockIdx.z == 0 ? W0 : (blockIdx.z == 1 ? W1 : W2);
    f16* O = Wt + (long)blockIdx.z * DIN * DOUT;
    int r0 = blockIdx.y * 64;   // in-dim
    int c0 = blockIdx.x * 64;   // out-dim
    int tx = threadIdx.x & 63, ty = threadIdx.x >> 6;
#pragma unroll
    for (int i = 0; i < 16; i++)
        tile[ty + i * 4][tx] = (f16)W[(long)(r0 + ty + i * 4) * DOUT + c0 + tx];
    __syncthreads();
#pragma unroll
    for (int i = 0; i < 16; i++)
        O[(long)(c0 + ty + i * 4) * DIN + r0 + tx] = tile[tx][ty + i * 4];
}

extern "C" void kernel_launch(void* const* d_in, const int* in_sizes, int n_in,
                              void* d_out, int out_size, void* d_ws, size_t ws_size,
                              hipStream_t stream) {
    const float* x  = (const float*)d_in[0];
    const float* Wq = (const float*)d_in[1];
    const float* Wk = (const float*)d_in[2];
    const float* Wv = (const float*)d_in[3];
    float* out = (float*)d_out;
    char* ws = (char*)d_ws;
    const size_t MB = 1ull << 20;
    // layout (71 MB):
    f16* xb  = (f16*)(ws);              // [0,8)   x f16; dead after QKV
    f16* Wt  = (f16*)(ws + 8 * MB);     // [8,14)  3x W^T f16; dead after QKV
    f16* Qb  = (f16*)(ws + 14 * MB);    // [14,22) dead after S GEMM
    f16* Kb  = (f16*)(ws + 22 * MB);    // [22,30) dead after S GEMM
    f16* Vt  = (f16*)(ws + 30 * MB);    // [30,38) V^T f16 [dout][seq]
    f16* S   = (f16*)(ws + 38 * MB);    // [38,70) P' = exp(s/32), f16
    float* Sums    = (float*)(ws);           // 1 MB over dead xb (row partials)
    float* scratch = (float*)(ws + 14 * MB); // 16 MB over dead Qb+Kb (PV partial)
    int*   flags   = (int*)(ws + 70 * MB);   // [70,70+2KB) DEDICATED, no alias
    // (R9/R10 bug: flags overlaid Wt which prep wrote after the memset.)

    // flags must be zero every call (ws is re-poisoned 0xAA by the harness)
    hipMemsetAsync(flags, 0, 2048, stream);
    prep<<<dim3(16, 16, 4), 256, 0, stream>>>(x, Wq, Wk, Wv, xb, Wt);
    // z=0: Q, z=1: K, z=2: V written transposed to Vt
    gemm_bt<f16, 1><<<dim3(8, 32, 3), 256, 0, stream>>>(
        xb, Wt, Qb, Kb, Qb, Qb, NSEQ, DOUT, DIN, DIN, DIN, DOUT, 1.0f,
        0, (long)DIN * DOUT, Vt, 2, NSEQ, nullptr, nullptr, nullptr);
    // P' = exp((Q @ K^T)/32) f16 + per-row partial sums (|s| <~ 2, so exp
    // needs no max subtraction; normalization happens in the PV epilogue)
    gemm_bt<f16, 2><<<dim3(32, 32, 1), 256, 0, stream>>>(
        Qb, Kb, S, S, S, S, NSEQ, NSEQ, DIN, DIN, DIN, NSEQ, 0.03125f,
        0, 0, nullptr, -1, 0, Sums, nullptr, nullptr);
    // out = (P' @ Vt^T) / rowsum, split-K=2 fused via completion protocol
    gemm_bt<float, 3><<<dim3(8, 32, 2), 256, 0, stream>>>(
        S, Vt, out, out, out, out, NSEQ, DOUT, 2048, NSEQ, NSEQ, DOUT, 1.0f,
        2048, 2048, nullptr, -1, 0, Sums, scratch, flags);
}

// Round 13
// 199.675 us; speedup vs baseline: 1.1222x; 1.1222x over previous
//
#include <hip/hip_runtime.h>
#include <math.h>

typedef _Float16 f16;
typedef __attribute__((ext_vector_type(8))) _Float16 f16x8;
typedef __attribute__((ext_vector_type(4))) _Float16 f16x4;
typedef __attribute__((ext_vector_type(4))) float f32x4;

#define NSEQ 4096
#define DIN 1024
#define DOUT 1024

// async global->LDS, 16B per lane; LDS dest must be wave-uniform base + lane*16
__device__ __forceinline__ void load16(const void* g, void* l) {
    __builtin_amdgcn_global_load_lds(
        (const __attribute__((address_space(1))) unsigned int*)g,
        (__attribute__((address_space(3))) unsigned int*)l, 16, 0, 0);
}

// C[M,N] = scale * (A[M,K] @ B[N,K]^T).  A,B f16.  128x128 tile, BK=64,
// single-buffered (R5/R8-measured best; jointly LDS+MFMA+L2 bound ~780 TF).
// z: A += z*aStrideZ, B += z*bStrideZ; C = cz (split-K / multi-output).
// EPI 1 (QKV): normal store, except z==tz writes f16 C^T to TC (ld=ldt).
// EPI 2 (S):   C = exp(acc*scale) f16 + per-(row, wave-col-half) partial sums
//              to Sums[row*64 + bx*2 + wn/64] (written once, no atomics).
// EPI 0 (PV):  plain store of acc*scale as OutT (f16 partials for split-K:
//              |numerator| <= ~200, normalized by rowsum ~4300 later, so f16
//              rounding contributes <~3e-5 to the output -- negligible).
template <typename OutT, int EPI>
__global__ __launch_bounds__(256, 2)
void gemm_bt(const f16* __restrict__ A, const f16* __restrict__ B,
             OutT* __restrict__ c0, OutT* __restrict__ c1,
             OutT* __restrict__ c2, OutT* __restrict__ c3,
             int M, int N, int K, int lda, int ldb, int ldc, float scale,
             long aStrideZ, long bStrideZ,
             f16* __restrict__ TC, int tz, int ldt, float* __restrict__ Sums)
{
    const int z = blockIdx.z;
    A += (long)z * aStrideZ;
    B += (long)z * bStrideZ;
    OutT* C = z == 0 ? c0 : (z == 1 ? c1 : (z == 2 ? c2 : c3));
    __shared__ f16 As[2 * 128 * 32];
    __shared__ f16 Bs[2 * 128 * 32];

    // ---- XCD patch swizzle (bijective remap of (bx,by)) ----
    int gx = gridDim.x;
    int bid = blockIdx.y * gx + blockIdx.x;
    int xcd = bid & 7, s = bid >> 3;
    int px = s & 7, rest = s >> 3;
    int py = rest & 3, chunk = rest >> 2;
    int pg = xcd + (chunk << 3);          // global patch id
    int pcols = gx >> 3;                  // patches per row (power of 2)
    int lp = 31 - __clz(pcols);
    int bx = ((pg & (pcols - 1)) << 3) + px;
    int by = ((pg >> lp) << 2) + py;

    const int t    = threadIdx.x;
    const int lane = t & 63;
    const int wave = t >> 6;
    const int wm   = (wave >> 1) * 64;
    const int wn   = (wave & 1) * 64;
    const int tile_m = by * 128;
    const int tile_n = bx * 128;
    const int quad = lane >> 4;
    const int l16  = lane & 15;
    // staging: thread t -> LDS chunk t (row t/4); global col chunk XOR-swizzled
    const int srow = t >> 2;
    const int scol = ((t & 3) ^ (srow & 3)) * 8;
    const int qx8 = (quad ^ (l16 & 3)) * 8;

    f32x4 acc[4][4];
#pragma unroll
    for (int i = 0; i < 4; i++)
#pragma unroll
        for (int j = 0; j < 4; j++)
            acc[i][j] = (f32x4){0.f, 0.f, 0.f, 0.f};

    const f16* Ab = A + (long)(tile_m + srow) * lda + scol;
    const f16* Bb = B + (long)(tile_n + srow) * ldb + scol;
    f16* Asd = As + t * 8;
    f16* Bsd = Bs + t * 8;

    for (int k0 = 0; k0 < K; k0 += 64) {
        load16(Ab + k0, Asd);
        load16(Ab + (long)64 * lda + k0, Asd + 2048);
        load16(Ab + k0 + 32, Asd + 4096);
        load16(Ab + (long)64 * lda + k0 + 32, Asd + 4096 + 2048);
        load16(Bb + k0, Bsd);
        load16(Bb + (long)64 * ldb + k0, Bsd + 2048);
        load16(Bb + k0 + 32, Bsd + 4096);
        load16(Bb + (long)64 * ldb + k0 + 32, Bsd + 4096 + 2048);
        __syncthreads();  // drains vmcnt(0); 32 MFMA/wave per drain
#pragma unroll
        for (int p = 0; p < 2; p++) {
            f16x8 a[4], b[4];
#pragma unroll
            for (int i = 0; i < 4; i++)
                a[i] = *(const f16x8*)(As + p * 4096 + (wm + i * 16 + l16) * 32 + qx8);
#pragma unroll
            for (int j = 0; j < 4; j++)
                b[j] = *(const f16x8*)(Bs + p * 4096 + (wn + j * 16 + l16) * 32 + qx8);
#pragma unroll
            for (int i = 0; i < 4; i++)
#pragma unroll
                for (int j = 0; j < 4; j++)
                    acc[i][j] = __builtin_amdgcn_mfma_f32_16x16x32_f16(
                        a[i], b[j], acc[i][j], 0, 0, 0);
        }
        __syncthreads();
    }
    // epilogue: D row = quad*4 + reg, col = lane&15  (verified m89/m91 layout)
    if (EPI == 1) {
        if (z == tz) {
            // transposed f16 write: TC[col*ldt + row], 8B per store (4 rows)
#pragma unroll
            for (int i = 0; i < 4; i++)
#pragma unroll
                for (int j = 0; j < 4; j++) {
                    f16x4 o;
#pragma unroll
                    for (int r = 0; r < 4; r++) o[r] = (f16)(acc[i][j][r] * scale);
                    int row0 = tile_m + wm + i * 16 + quad * 4;
                    int col  = tile_n + wn + j * 16 + l16;
                    *(f16x4*)(TC + (long)col * ldt + row0) = o;
                }
        } else {
#pragma unroll
            for (int i = 0; i < 4; i++)
#pragma unroll
                for (int j = 0; j < 4; j++)
#pragma unroll
                    for (int r = 0; r < 4; r++) {
                        int row = tile_m + wm + i * 16 + quad * 4 + r;
                        int col = tile_n + wn + j * 16 + l16;
                        C[(long)row * ldc + col] = (OutT)(acc[i][j][r] * scale);
                    }
        }
    } else if (EPI == 2) {
        // P' = exp(s*scale), plus per-row partial sums over this wave's 64 cols
        const int bxs = bx * 2 + (wn >> 6);
#pragma unroll
        for (int i = 0; i < 4; i++) {
            float rs[4] = {0.f, 0.f, 0.f, 0.f};
#pragma unroll
            for (int j = 0; j < 4; j++)
#pragma unroll
                for (int r = 0; r < 4; r++) {
                    float e = __expf(acc[i][j][r] * scale);
                    int row = tile_m + wm + i * 16 + quad * 4 + r;
                    int col = tile_n + wn + j * 16 + l16;
                    C[(long)row * ldc + col] = (OutT)e;
                    rs[r] += e;
                }
#pragma unroll
            for (int msk = 1; msk < 16; msk <<= 1)
#pragma unroll
                for (int r = 0; r < 4; r++)
                    rs[r] += __shfl_xor(rs[r], msk, 64);
            if (l16 == 0)
#pragma unroll
                for (int r = 0; r < 4; r++) {
                    int row = tile_m + wm + i * 16 + quad * 4 + r;
                    Sums[(long)row * 64 + bxs] = rs[r];
                }
        }
    } else {
#pragma unroll
        for (int i = 0; i < 4; i++)
#pragma unroll
            for (int j = 0; j < 4; j++)
#pragma unroll
                for (int r = 0; r < 4; r++) {
                    int row = tile_m + wm + i * 16 + quad * 4 + r;
                    int col = tile_n + wn + j * 16 + l16;
                    C[(long)row * ldc + col] = (OutT)(acc[i][j][r] * scale);
                }
    }
}

// z<3: transpose+cast W_z fp32[in][out] -> Wt_z f16[out][in]; z==3: cast x->f16
__global__ void prep(const float* __restrict__ x,
                     const float* __restrict__ W0, const float* __restrict__ W1,
                     const float* __restrict__ W2,
                     f16* __restrict__ xb, f16* __restrict__ Wt) {
    if (blockIdx.z == 3) {
        long base = ((long)(blockIdx.y * 16 + blockIdx.x) * 256 + threadIdx.x) * 4;
#pragma unroll
        for (int it = 0; it < 16; it++) {
            long i = base + (long)it * (256 * 256 * 4);
            f32x4 v = *(const f32x4*)(x + i);
            f16x4 o;
            o.x = (f16)v.x; o.y = (f16)v.y; o.z = (f16)v.z; o.w = (f16)v.w;
            *(f16x4*)(xb + i) = o;
        }
        return;
    }
    __shared__ f16 tile[64][65];
    const float* W = blockIdx.z == 0 ? W0 : (blockIdx.z == 1 ? W1 : W2);
    f16* O = Wt + (long)blockIdx.z * DIN * DOUT;
    int r0 = blockIdx.y * 64;   // in-dim
    int c0 = blockIdx.x * 64;   // out-dim
    int tx = threadIdx.x & 63, ty = threadIdx.x >> 6;
#pragma unroll
    for (int i = 0; i < 16; i++)
        tile[ty + i * 4][tx] = (f16)W[(long)(r0 + ty + i * 4) * DOUT + c0 + tx];
    __syncthreads();
#pragma unroll
    for (int i = 0; i < 16; i++)
        O[(long)(c0 + ty + i * 4) * DIN + r0 + tx] = tile[tx][ty + i * 4];
}

// out = (p0+p1+p2+p3)/rowsum ; one block per output row; partials are f16.
// rowsum = sum of the 64 per-wave partials written by the EPI-2 epilogue.
__global__ __launch_bounds__(256)
void reduce_norm(const f16* __restrict__ p0, const f16* __restrict__ p1,
                 const f16* __restrict__ p2, const f16* __restrict__ p3,
                 const float* __restrict__ sums, float* __restrict__ out) {
    const int row = blockIdx.x;
    const int lane = threadIdx.x & 63;
    float s = sums[(long)row * 64 + lane];   // each wave reduces redundantly
#pragma unroll
    for (int msk = 1; msk < 64; msk <<= 1) s += __shfl_xor(s, msk, 64);
    const float inv = 1.f / s;
    long i = (long)row * 1024 + threadIdx.x * 4;
    f16x4 a = *(const f16x4*)(p0 + i);
    f16x4 b = *(const f16x4*)(p1 + i);
    f16x4 c = *(const f16x4*)(p2 + i);
    f16x4 d = *(const f16x4*)(p3 + i);
    f32x4 o;
    o.x = (((float)a.x + (float)b.x) + ((float)c.x + (float)d.x)) * inv;
    o.y = (((float)a.y + (float)b.y) + ((float)c.y + (float)d.y)) * inv;
    o.z = (((float)a.z + (float)b.z) + ((float)c.z + (float)d.z)) * inv;
    o.w = (((float)a.w + (float)b.w) + ((float)c.w + (float)d.w)) * inv;
    *(f32x4*)(out + i) = o;
}

extern "C" void kernel_launch(void* const* d_in, const int* in_sizes, int n_in,
                              void* d_out, int out_size, void* d_ws, size_t ws_size,
                              hipStream_t stream) {
    const float* x  = (const float*)d_in[0];
    const float* Wq = (const float*)d_in[1];
    const float* Wk = (const float*)d_in[2];
    const float* Wv = (const float*)d_in[3];
    float* out = (float*)d_out;
    char* ws = (char*)d_ws;
    const size_t MB = 1ull << 20;
    // layout (102 MB peak):
    f16* xb  = (f16*)(ws);              // [0,8)   x f16; dead after QKV
    f16* Wt  = (f16*)(ws + 8 * MB);     // [8,14)  3x W^T f16
    f16* Qb  = (f16*)(ws + 14 * MB);    // [14,22) dead after S GEMM
    f16* Kb  = (f16*)(ws + 22 * MB);    // [22,30) dead after S GEMM
    f16* Vt  = (f16*)(ws + 30 * MB);    // [30,38) V^T f16 [dout][seq]
    f16* S   = (f16*)(ws + 38 * MB);    // [38,70) P' = exp(s/32), f16
    f16* scr0 = (f16*)(ws + 70 * MB);   // [70,78)  f16 PV partial 0
    f16* scr1 = (f16*)(ws + 78 * MB);   // [78,86)  f16 PV partial 1
    f16* scr2 = (f16*)(ws + 86 * MB);   // [86,94)  f16 PV partial 2
    f16* scr3 = (f16*)(ws + 94 * MB);   // [94,102) f16 PV partial 3
    float* Sums = (float*)(ws);         // 1 MB over dead xb (row partial sums)

    prep<<<dim3(16, 16, 4), 256, 0, stream>>>(x, Wq, Wk, Wv, xb, Wt);
    // z=0: Q, z=1: K, z=2: V written transposed to Vt
    gemm_bt<f16, 1><<<dim3(8, 32, 3), 256, 0, stream>>>(
        xb, Wt, Qb, Kb, Qb, Qb, NSEQ, DOUT, DIN, DIN, DIN, DOUT, 1.0f,
        0, (long)DIN * DOUT, Vt, 2, NSEQ, nullptr);
    // P' = exp((Q @ K^T)/32) f16 + per-row partial sums (|s| <~ 2, so exp
    // needs no max subtraction; normalization happens in reduce_norm)
    gemm_bt<f16, 2><<<dim3(32, 32, 1), 256, 0, stream>>>(
        Qb, Kb, S, S, S, S, NSEQ, NSEQ, DIN, DIN, DIN, NSEQ, 0.03125f,
        0, 0, nullptr, -1, 0, Sums);
    // partial_z = P'[:, z*1024:(z+1)*1024] @ Vt[:, z*1024:(z+1)*1024]^T (f16)
    gemm_bt<f16, 0><<<dim3(8, 32, 4), 256, 0, stream>>>(
        S, Vt, scr0, scr1, scr2, scr3, NSEQ, DOUT, 1024, NSEQ, NSEQ, DOUT, 1.0f,
        1024, 1024, nullptr, -1, 0, nullptr);
    reduce_norm<<<4096, 256, 0, stream>>>(scr0, scr1, scr2, scr3, Sums, out);
}